// Round 5
// baseline (182.957 us; speedup 1.0000x reference)
//
#include <hip/hip_runtime.h>
#include <math.h>

// QMIX mixing network, B=65536, A=8, S=256, E=32. All tensors fp32.
// Transposed MFMA: A-operand = bf16(Wcat^T) fragments (m = out col),
// B-operand = bf16(states) (n = batch row), mfma_f32_16x16x32_bf16.
// Dual-B: each wave computes 32 batch rows (2 row-groups share each A-frag).
// Weight tiles 0..7 live in 64 KB LDS (staged once, single barrier);
// tiles 8..21 stream from L2 with deep unrolled pipelining.
// Wcat columns: [0,256)=w1_W, [256,288)=wf_W, [288,320)=b1_W, [320,352)=v1_W.

#define NTILES 22      // 352/16
#define KCHUNKS 8      // 256/32
#define LDS_T  8       // tiles resident in LDS (64 KB exactly)

typedef __attribute__((ext_vector_type(8))) short short8;
typedef __attribute__((ext_vector_type(4))) float float4v;
typedef __attribute__((ext_vector_type(4))) int int4v;

__device__ __forceinline__ unsigned short f2b(float f) {
    unsigned int u = __float_as_uint(f);
    u = u + 0x7fffu + ((u >> 16) & 1u);   // RNE
    return (unsigned short)(u >> 16);
}

// Repack fp32 Wcat into bf16 A-fragment order, slot = t*8 + kc (t-major so
// the first 64 slots = tiles 0..7 are a contiguous 64 KB LDS image):
// brep[(slot*64 + lane)*8 + j] = bf16(Wcat[k = kc*32+(lane>>4)*8+j][t*16+(lane&15)])
__global__ void repack_b(const float* __restrict__ w1_W,
                         const float* __restrict__ wf_W,
                         const float* __restrict__ b1_W,
                         const float* __restrict__ v1_W,
                         unsigned short* __restrict__ brep) {
    int idx = blockIdx.x * 256 + threadIdx.x;   // 0..11263
    int lane = idx & 63;
    int tk   = idx >> 6;          // t*8 + kc
    int t    = tk >> 3;
    int kc   = tk & 7;
    int kbase = kc * 32 + (lane >> 4) * 8;
    int n = t * 16 + (lane & 15);
    short8 frag;
#pragma unroll
    for (int j = 0; j < 8; ++j) {
        int k = kbase + j;
        float val;
        if (n < 256)      val = w1_W[k * 256 + n];
        else if (n < 288) val = wf_W[k * 32 + (n - 256)];
        else if (n < 320) val = b1_W[k * 32 + (n - 288)];
        else              val = v1_W[k * 32 + (n - 320)];
        frag[j] = (short)f2b(val);
    }
    *(short8*)(&brep[idx * 8]) = frag;
}

__global__ void __launch_bounds__(256, 1)
qmix_main(const float* __restrict__ agent_qs,
          const float* __restrict__ states,
          const unsigned short* __restrict__ brep,
          const float* __restrict__ w1_b,
          const float* __restrict__ wf_b,
          const float* __restrict__ b1_b,
          const float* __restrict__ v1_b,
          const float* __restrict__ v2_W,
          const float* __restrict__ v2_b,
          float* __restrict__ out) {
    __shared__ __align__(16) unsigned short wlds[LDS_T * KCHUNKS * 64 * 8]; // 65536 B

    const int tid  = threadIdx.x;
    const int wave = tid >> 6, lane = tid & 63;
    const int quad = lane >> 4, l16 = lane & 15;
    const int r0 = blockIdx.x * 128 + wave * 32 + l16;   // row-group 0; group 1 = +16

    // ---- B fragments for both row-groups: bfr[g][kc] (issued before staging) ----
    short8 bfr[2][KCHUNKS];
#pragma unroll
    for (int g = 0; g < 2; ++g) {
        const float* srow = states + (size_t)(r0 + g * 16) * 256;
#pragma unroll
        for (int kc = 0; kc < KCHUNKS; ++kc) {
            float4v a0 = *(const float4v*)(srow + kc * 32 + quad * 8);
            float4v a1 = *(const float4v*)(srow + kc * 32 + quad * 8 + 4);
            short8 bf;
#pragma unroll
            for (int j = 0; j < 4; ++j) {
                bf[j]     = (short)f2b(a0[j]);
                bf[4 + j] = (short)f2b(a1[j]);
            }
            bfr[g][kc] = bf;
        }
    }

    // ---- Stage tiles 0..7 (first 64 KB of brep) into LDS, coalesced ----
    {
        const int4v* src = (const int4v*)brep;
        int4v* dst = (int4v*)wlds;
#pragma unroll
        for (int i = 0; i < 16; ++i)
            dst[tid + i * 256] = src[tid + i * 256];
    }
    __syncthreads();   // the only barrier; wlds is read-only below

    float4v acc[2][NTILES];
#pragma unroll
    for (int g = 0; g < 2; ++g)
#pragma unroll
        for (int t = 0; t < NTILES; ++t)
#pragma unroll
            for (int q = 0; q < 4; ++q) acc[g][t][q] = 0.f;

    // ---- K loop, fully unrolled: one A-frag feeds 2 MFMAs ----
    const short8* wl = (const short8*)wlds + lane;   // + (t*8+kc)*64, t < 8
    const short8* ws = (const short8*)brep + lane;   // + (t*8+kc)*64, t >= 8
#pragma unroll
    for (int kc = 0; kc < KCHUNKS; ++kc) {
        short8 b0 = bfr[0][kc], b1 = bfr[1][kc];
#pragma unroll
        for (int t = 0; t < NTILES; ++t) {
            short8 af = (t < LDS_T) ? wl[(t * 8 + kc) * 64] : ws[(t * 8 + kc) * 64];
            acc[0][t] = __builtin_amdgcn_mfma_f32_16x16x32_bf16(af, b0, acc[0][t], 0, 0, 0);
            acc[1][t] = __builtin_amdgcn_mfma_f32_16x16x32_bf16(af, b1, acc[1][t], 0, 0, 0);
        }
    }

    // ---- Epilogue (per row-group, all in registers; R4-verified mapping) ----
#pragma unroll
    for (int g = 0; g < 2; ++g) {
        const int row = r0 + g * 16;
        float4v q0 = *(const float4v*)(agent_qs + (size_t)row * 8);
        float4v q1 = *(const float4v*)(agent_qs + (size_t)row * 8 + 4);
        float qv[8] = {q0[0], q0[1], q0[2], q0[3], q1[0], q1[1], q1[2], q1[3]};

        float qacc[8], wfv[8], b1v[8], svp = 0.f;
#pragma unroll
        for (int s = 0; s < 8; ++s) qacc[s] = 0.f;

#pragma unroll
        for (int t = 0; t < NTILES; ++t) {
            const float* bptr =
                (t < 16) ? (w1_b + t * 16) :
                (t < 18) ? (wf_b + (t - 16) * 16) :
                (t < 20) ? (b1_b + (t - 18) * 16) : (v1_b + (t - 20) * 16);
            float4v bb = *(const float4v*)(bptr + quad * 4);
            float vb[4];
#pragma unroll
            for (int j = 0; j < 4; ++j) vb[j] = acc[g][t][j] + bb[j];

            if (t < 16) {              // w1: agent a = t>>1, slot base = (t&1)*4
                float q = qv[t >> 1];
                int base = (t & 1) * 4;
#pragma unroll
                for (int j = 0; j < 4; ++j) qacc[base + j] += q * fabsf(vb[j]);
            } else if (t < 18) {       // w_final
                int base = (t - 16) * 4;
#pragma unroll
                for (int j = 0; j < 4; ++j) wfv[base + j] = fabsf(vb[j]);
            } else if (t < 20) {       // b1
                int base = (t - 18) * 4;
#pragma unroll
                for (int j = 0; j < 4; ++j) b1v[base + j] = vb[j];
            } else {                   // V hidden: relu -> dot v2_W
                int ebase = (t - 20) * 16 + quad * 4;
#pragma unroll
                for (int j = 0; j < 4; ++j)
                    svp += fmaxf(vb[j], 0.f) * v2_W[ebase + j];
            }
        }

        float mix = 0.f;
#pragma unroll
        for (int s = 0; s < 8; ++s) {
            float h = qacc[s] + b1v[s];
            h = h > 0.f ? h : (__expf(h) - 1.f);   // elu, alpha=1
            mix += h * wfv[s];
        }
        float tot = mix + svp;                      // partial over this quad's e-subset
        tot += __shfl_xor(tot, 16);                 // combine 4 quads (same batch row)
        tot += __shfl_xor(tot, 32);
        if (quad == 0) out[row] = tot + v2_b[0];
    }
}

extern "C" void kernel_launch(void* const* d_in, const int* in_sizes, int n_in,
                              void* d_out, int out_size, void* d_ws, size_t ws_size,
                              hipStream_t stream) {
    const float* agent_qs = (const float*)d_in[0];
    const float* states   = (const float*)d_in[1];
    const float* w1_W = (const float*)d_in[2];
    const float* w1_b = (const float*)d_in[3];
    const float* wf_W = (const float*)d_in[4];
    const float* wf_b = (const float*)d_in[5];
    const float* b1_W = (const float*)d_in[6];
    const float* b1_b = (const float*)d_in[7];
    const float* v1_W = (const float*)d_in[8];
    const float* v1_b = (const float*)d_in[9];
    const float* v2_W = (const float*)d_in[10];
    const float* v2_b = (const float*)d_in[11];
    float* out = (float*)d_out;
    unsigned short* brep = (unsigned short*)d_ws;    // 180224 B of scratch

    repack_b<<<44, 256, 0, stream>>>(w1_W, wf_W, b1_W, v1_W, brep);
    qmix_main<<<512, 256, 0, stream>>>(agent_qs, states, brep,
                                       w1_b, wf_b, b1_b, v1_b, v2_W, v2_b, out);
}

// Round 6
// 129.027 us; speedup vs baseline: 1.4180x; 1.4180x over previous
//
#include <hip/hip_runtime.h>
#include <math.h>

// QMIX mixing network, B=65536, A=8, S=256, E=32. All tensors fp32.
// Transposed MFMA: A-operand = bf16(Wcat^T) fragments (m = out col),
// B-operand = bf16(states) (n = batch row), mfma_f32_16x16x32_bf16.
// Dual-B: each wave computes 32 batch rows; block = 128 rows (4 waves).
// Weights staged per k-chunk (22.5 KB) into a double-buffered LDS (45 KB),
// prefetched global->VGPR->ds_write overlapping the MFMA phase; one barrier
// per chunk. States fragments software-pipelined one chunk ahead.
// Wcat columns: [0,256)=w1_W, [256,288)=wf_W, [288,320)=b1_W, [320,352)=v1_W.

#define NTILES 22      // 352/16
#define KCHUNKS 8      // 256/32
#define CHUNK_I4 1408  // 16B units per k-chunk (22528 B)

typedef __attribute__((ext_vector_type(8))) short short8;
typedef __attribute__((ext_vector_type(4))) float float4v;
typedef __attribute__((ext_vector_type(4))) int int4v;

__device__ __forceinline__ unsigned short f2b(float f) {
    unsigned int u = __float_as_uint(f);
    u = u + 0x7fffu + ((u >> 16) & 1u);   // RNE
    return (unsigned short)(u >> 16);
}

// Repack fp32 Wcat into bf16 A-fragment order, slot = kc*22 + t (kc-major:
// each k-chunk is a contiguous 22528 B block — validated in R2-R4):
// brep[(slot*64 + lane)*8 + j] = bf16(Wcat[k = kc*32+(lane>>4)*8+j][t*16+(lane&15)])
__global__ void repack_b(const float* __restrict__ w1_W,
                         const float* __restrict__ wf_W,
                         const float* __restrict__ b1_W,
                         const float* __restrict__ v1_W,
                         unsigned short* __restrict__ brep) {
    int idx = blockIdx.x * 256 + threadIdx.x;   // 0..11263
    int lane = idx & 63;
    int tt   = idx >> 6;          // kc*22 + t
    int t    = tt % 22;
    int kc   = tt / 22;
    int kbase = kc * 32 + (lane >> 4) * 8;
    int n = t * 16 + (lane & 15);
    short8 frag;
#pragma unroll
    for (int j = 0; j < 8; ++j) {
        int k = kbase + j;
        float val;
        if (n < 256)      val = w1_W[k * 256 + n];
        else if (n < 288) val = wf_W[k * 32 + (n - 256)];
        else if (n < 320) val = b1_W[k * 32 + (n - 288)];
        else              val = v1_W[k * 32 + (n - 320)];
        frag[j] = (short)f2b(val);
    }
    *(short8*)(&brep[idx * 8]) = frag;
}

__global__ void __launch_bounds__(256, 2)
qmix_main(const float* __restrict__ agent_qs,
          const float* __restrict__ states,
          const unsigned short* __restrict__ brep,
          const float* __restrict__ w1_b,
          const float* __restrict__ wf_b,
          const float* __restrict__ b1_b,
          const float* __restrict__ v1_b,
          const float* __restrict__ v2_W,
          const float* __restrict__ v2_b,
          float* __restrict__ out) {
    __shared__ __align__(16) unsigned short wlds[2][NTILES * 64 * 8];  // 2 x 22528 B

    const int tid  = threadIdx.x;
    const int wave = tid >> 6, lane = tid & 63;
    const int quad = lane >> 4, l16 = lane & 15;
    const int r0 = blockIdx.x * 128 + wave * 32 + l16;   // group 0 row; group 1 = +16
    const float* srow0 = states + (size_t)r0 * 256;
    const float* srow1 = srow0 + 16 * 256;

    // ---- Stage chunk 0 into buffer 0 (through VGPRs, coalesced 16B) ----
    {
        const int4v* src = (const int4v*)brep;
        int4v* dst = (int4v*)wlds[0];
        int4v tmp[6];
#pragma unroll
        for (int i = 0; i < 5; ++i) tmp[i] = src[tid + i * 256];
        if (tid < 128) tmp[5] = src[1280 + tid];
#pragma unroll
        for (int i = 0; i < 5; ++i) dst[tid + i * 256] = tmp[i];
        if (tid < 128) dst[1280 + tid] = tmp[5];
    }

    // ---- Preload states fragments for chunk 0 ----
    float4v s0a = *(const float4v*)(srow0 + quad * 8);
    float4v s0b = *(const float4v*)(srow0 + quad * 8 + 4);
    float4v s1a = *(const float4v*)(srow1 + quad * 8);
    float4v s1b = *(const float4v*)(srow1 + quad * 8 + 4);

    float4v acc[2][NTILES];
#pragma unroll
    for (int g = 0; g < 2; ++g)
#pragma unroll
        for (int t = 0; t < NTILES; ++t)
#pragma unroll
            for (int q = 0; q < 4; ++q) acc[g][t][q] = 0.f;

    __syncthreads();

    const unsigned short* bufc = wlds[0];
    unsigned short* bufn = wlds[1];

    for (int kc = 0; kc < KCHUNKS; ++kc) {
        // Prefetch next weight chunk global -> VGPR (completes during MFMA phase)
        int4v tmp[6];
        if (kc < KCHUNKS - 1) {
            const int4v* src = (const int4v*)brep + (kc + 1) * CHUNK_I4;
#pragma unroll
            for (int i = 0; i < 5; ++i) tmp[i] = src[tid + i * 256];
            if (tid < 128) tmp[5] = src[1280 + tid];
        }
        // Convert current states frags to bf16
        short8 b0, b1;
#pragma unroll
        for (int j = 0; j < 4; ++j) {
            b0[j] = (short)f2b(s0a[j]); b0[4 + j] = (short)f2b(s0b[j]);
            b1[j] = (short)f2b(s1a[j]); b1[4 + j] = (short)f2b(s1b[j]);
        }
        // Prefetch next states frags
        if (kc < KCHUNKS - 1) {
            const float* p0 = srow0 + (kc + 1) * 32 + quad * 8;
            const float* p1 = srow1 + (kc + 1) * 32 + quad * 8;
            s0a = *(const float4v*)(p0);
            s0b = *(const float4v*)(p0 + 4);
            s1a = *(const float4v*)(p1);
            s1b = *(const float4v*)(p1 + 4);
        }
        // MFMA phase on current buffer: 22 ds_read_b128 feed 44 MFMAs
        const short8* wb = (const short8*)bufc + lane;
#pragma unroll
        for (int t = 0; t < NTILES; ++t) {
            short8 af = wb[t * 64];
            acc[0][t] = __builtin_amdgcn_mfma_f32_16x16x32_bf16(af, b0, acc[0][t], 0, 0, 0);
            acc[1][t] = __builtin_amdgcn_mfma_f32_16x16x32_bf16(af, b1, acc[1][t], 0, 0, 0);
        }
        // Write prefetched chunk to the other buffer
        if (kc < KCHUNKS - 1) {
            int4v* dst = (int4v*)bufn;
#pragma unroll
            for (int i = 0; i < 5; ++i) dst[tid + i * 256] = tmp[i];
            if (tid < 128) dst[1280 + tid] = tmp[5];
        }
        // Swap buffers
        const unsigned short* tswap = bufc;
        bufc = bufn;
        bufn = (unsigned short*)tswap;
        __syncthreads();
    }

    // ---- Epilogue (per row-group, all in registers; R4/R5-verified mapping) ----
#pragma unroll
    for (int g = 0; g < 2; ++g) {
        const int row = r0 + g * 16;
        float4v q0 = *(const float4v*)(agent_qs + (size_t)row * 8);
        float4v q1 = *(const float4v*)(agent_qs + (size_t)row * 8 + 4);
        float qv[8] = {q0[0], q0[1], q0[2], q0[3], q1[0], q1[1], q1[2], q1[3]};

        float qacc[8], wfv[8], b1v[8], svp = 0.f;
#pragma unroll
        for (int s = 0; s < 8; ++s) qacc[s] = 0.f;

#pragma unroll
        for (int t = 0; t < NTILES; ++t) {
            const float* bptr =
                (t < 16) ? (w1_b + t * 16) :
                (t < 18) ? (wf_b + (t - 16) * 16) :
                (t < 20) ? (b1_b + (t - 18) * 16) : (v1_b + (t - 20) * 16);
            float4v bb = *(const float4v*)(bptr + quad * 4);
            float vb[4];
#pragma unroll
            for (int j = 0; j < 4; ++j) vb[j] = acc[g][t][j] + bb[j];

            if (t < 16) {              // w1: agent a = t>>1, slot base = (t&1)*4
                float q = qv[t >> 1];
                int base = (t & 1) * 4;
#pragma unroll
                for (int j = 0; j < 4; ++j) qacc[base + j] += q * fabsf(vb[j]);
            } else if (t < 18) {       // w_final
                int base = (t - 16) * 4;
#pragma unroll
                for (int j = 0; j < 4; ++j) wfv[base + j] = fabsf(vb[j]);
            } else if (t < 20) {       // b1
                int base = (t - 18) * 4;
#pragma unroll
                for (int j = 0; j < 4; ++j) b1v[base + j] = vb[j];
            } else {                   // V hidden: relu -> dot v2_W
                int ebase = (t - 20) * 16 + quad * 4;
#pragma unroll
                for (int j = 0; j < 4; ++j)
                    svp += fmaxf(vb[j], 0.f) * v2_W[ebase + j];
            }
        }

        float mix = 0.f;
#pragma unroll
        for (int s = 0; s < 8; ++s) {
            float h = qacc[s] + b1v[s];
            h = h > 0.f ? h : (__expf(h) - 1.f);   // elu, alpha=1
            mix += h * wfv[s];
        }
        float tot = mix + svp;                      // partial over this quad's e-subset
        tot += __shfl_xor(tot, 16);                 // combine 4 quads (same batch row)
        tot += __shfl_xor(tot, 32);
        if (quad == 0) out[row] = tot + v2_b[0];
    }
}

extern "C" void kernel_launch(void* const* d_in, const int* in_sizes, int n_in,
                              void* d_out, int out_size, void* d_ws, size_t ws_size,
                              hipStream_t stream) {
    const float* agent_qs = (const float*)d_in[0];
    const float* states   = (const float*)d_in[1];
    const float* w1_W = (const float*)d_in[2];
    const float* w1_b = (const float*)d_in[3];
    const float* wf_W = (const float*)d_in[4];
    const float* wf_b = (const float*)d_in[5];
    const float* b1_W = (const float*)d_in[6];
    const float* b1_b = (const float*)d_in[7];
    const float* v1_W = (const float*)d_in[8];
    const float* v1_b = (const float*)d_in[9];
    const float* v2_W = (const float*)d_in[10];
    const float* v2_b = (const float*)d_in[11];
    float* out = (float*)d_out;
    unsigned short* brep = (unsigned short*)d_ws;    // 180224 B of scratch

    repack_b<<<44, 256, 0, stream>>>(w1_W, wf_W, b1_W, v1_W, brep);
    qmix_main<<<512, 256, 0, stream>>>(agent_qs, states, brep,
                                       w1_b, wf_b, b1_b, v1_b, v2_W, v2_b, out);
}

// Round 7
// 127.039 us; speedup vs baseline: 1.4402x; 1.0156x over previous
//
#include <hip/hip_runtime.h>
#include <math.h>

// QMIX mixing network, B=65536, A=8, S=256, E=32. All tensors fp32.
// Transposed MFMA: A-operand = bf16(Wcat^T) fragments (m = out col),
// B-operand = bf16(states) (n = batch row), mfma_f32_16x16x32_bf16.
// Dual-B: each wave computes 32 batch rows; block = 128 rows (4 waves).
// Weights staged per k-chunk (22.5 KB) into double-buffered LDS via
// global_load_lds width=16 (direct DMA, no VGPR round-trip), prefetched one
// chunk ahead overlapping the MFMA phase; one barrier per chunk. States
// fragments software-pipelined one chunk ahead in VGPRs.
// Wcat columns: [0,256)=w1_W, [256,288)=wf_W, [288,320)=b1_W, [320,352)=v1_W.

#define NTILES 22      // 352/16
#define KCHUNKS 8      // 256/32
#define CHUNK_I4 1408  // 16B units per k-chunk (22528 B)

typedef __attribute__((ext_vector_type(8))) short short8;
typedef __attribute__((ext_vector_type(4))) float float4v;

__device__ __forceinline__ unsigned short f2b(float f) {
    unsigned int u = __float_as_uint(f);
    u = u + 0x7fffu + ((u >> 16) & 1u);   // RNE
    return (unsigned short)(u >> 16);
}

// Direct global->LDS DMA, 16 B/lane. LDS dest = wave-uniform base + lane*16.
__device__ __forceinline__ void gl2lds16(const unsigned short* g, unsigned short* l) {
    __builtin_amdgcn_global_load_lds(
        (const __attribute__((address_space(1))) unsigned int*)g,
        (__attribute__((address_space(3))) unsigned int*)l,
        16, 0, 0);
}

// Repack fp32 Wcat into bf16 A-fragment order, slot = kc*22 + t (kc-major:
// each k-chunk is a contiguous 22528 B block — validated R2-R6):
// brep[(slot*64 + lane)*8 + j] = bf16(Wcat[k = kc*32+(lane>>4)*8+j][t*16+(lane&15)])
__global__ void repack_b(const float* __restrict__ w1_W,
                         const float* __restrict__ wf_W,
                         const float* __restrict__ b1_W,
                         const float* __restrict__ v1_W,
                         unsigned short* __restrict__ brep) {
    int idx = blockIdx.x * 256 + threadIdx.x;   // 0..11263
    int lane = idx & 63;
    int tt   = idx >> 6;          // kc*22 + t
    int t    = tt % 22;
    int kc   = tt / 22;
    int kbase = kc * 32 + (lane >> 4) * 8;
    int n = t * 16 + (lane & 15);
    short8 frag;
#pragma unroll
    for (int j = 0; j < 8; ++j) {
        int k = kbase + j;
        float val;
        if (n < 256)      val = w1_W[k * 256 + n];
        else if (n < 288) val = wf_W[k * 32 + (n - 256)];
        else if (n < 320) val = b1_W[k * 32 + (n - 288)];
        else              val = v1_W[k * 32 + (n - 320)];
        frag[j] = (short)f2b(val);
    }
    *(short8*)(&brep[idx * 8]) = frag;
}

__global__ void __launch_bounds__(256, 2)
qmix_main(const float* __restrict__ agent_qs,
          const float* __restrict__ states,
          const unsigned short* __restrict__ brep,
          const float* __restrict__ w1_b,
          const float* __restrict__ wf_b,
          const float* __restrict__ b1_b,
          const float* __restrict__ v1_b,
          const float* __restrict__ v2_W,
          const float* __restrict__ v2_b,
          float* __restrict__ out) {
    __shared__ __align__(16) unsigned short wlds[2][NTILES * 64 * 8];  // 2 x 22528 B

    const int tid  = threadIdx.x;
    const int wave = tid >> 6, lane = tid & 63;
    const int quad = lane >> 4, l16 = lane & 15;
    const int r0 = blockIdx.x * 128 + wave * 32 + l16;   // group 0 row; group 1 = +16
    const float* srow0 = states + (size_t)r0 * 256;
    const float* srow1 = srow0 + 16 * 256;

    // ---- Stage chunk 0 into buffer 0 via direct DMA.
    // 22 wave-instrs per chunk: slot s -> wave s&3, LDS base slot*1024 B (uniform),
    // global 16B-unit = chunk_base + s*64 + lane. Same layout as R6 (validated).
    for (int s = wave; s < NTILES; s += 4)
        gl2lds16(brep + (size_t)(s * 64 + lane) * 8, wlds[0] + s * 512);

    // ---- Preload states fragments for chunk 0 ----
    float4v s0a = *(const float4v*)(srow0 + quad * 8);
    float4v s0b = *(const float4v*)(srow0 + quad * 8 + 4);
    float4v s1a = *(const float4v*)(srow1 + quad * 8);
    float4v s1b = *(const float4v*)(srow1 + quad * 8 + 4);

    float4v acc[2][NTILES];
#pragma unroll
    for (int g = 0; g < 2; ++g)
#pragma unroll
        for (int t = 0; t < NTILES; ++t)
#pragma unroll
            for (int q = 0; q < 4; ++q) acc[g][t][q] = 0.f;

    __syncthreads();   // drains chunk-0 DMA (vmcnt 0) for all waves

    int cur = 0;
    for (int kc = 0; kc < KCHUNKS; ++kc) {
        // Prefetch next weight chunk straight into the other LDS buffer; the
        // DMA flies during this chunk's MFMA phase, drained by the barrier.
        if (kc < KCHUNKS - 1) {
            const unsigned short* src = brep + (size_t)(kc + 1) * CHUNK_I4 * 8;
            unsigned short* dst = wlds[cur ^ 1];
            for (int s = wave; s < NTILES; s += 4)
                gl2lds16(src + (size_t)(s * 64 + lane) * 8, dst + s * 512);
        }
        // Convert current states frags to bf16
        short8 b0, b1;
#pragma unroll
        for (int j = 0; j < 4; ++j) {
            b0[j] = (short)f2b(s0a[j]); b0[4 + j] = (short)f2b(s0b[j]);
            b1[j] = (short)f2b(s1a[j]); b1[4 + j] = (short)f2b(s1b[j]);
        }
        // Prefetch next states frags (VGPR pipeline, one chunk ahead)
        if (kc < KCHUNKS - 1) {
            const float* p0 = srow0 + (kc + 1) * 32 + quad * 8;
            const float* p1 = srow1 + (kc + 1) * 32 + quad * 8;
            s0a = *(const float4v*)(p0);
            s0b = *(const float4v*)(p0 + 4);
            s1a = *(const float4v*)(p1);
            s1b = *(const float4v*)(p1 + 4);
        }
        // MFMA phase on current buffer: 22 ds_read_b128 feed 44 MFMAs
        const short8* wb = (const short8*)wlds[cur] + lane;
#pragma unroll
        for (int t = 0; t < NTILES; ++t) {
            short8 af = wb[t * 64];
            acc[0][t] = __builtin_amdgcn_mfma_f32_16x16x32_bf16(af, b0, acc[0][t], 0, 0, 0);
            acc[1][t] = __builtin_amdgcn_mfma_f32_16x16x32_bf16(af, b1, acc[1][t], 0, 0, 0);
        }
        cur ^= 1;
        __syncthreads();   // WAR on read buffer + drain of next chunk's DMA
    }

    // ---- Epilogue (per row-group, all in registers; R4-R6 verified mapping) ----
#pragma unroll
    for (int g = 0; g < 2; ++g) {
        const int row = r0 + g * 16;
        float4v q0 = *(const float4v*)(agent_qs + (size_t)row * 8);
        float4v q1 = *(const float4v*)(agent_qs + (size_t)row * 8 + 4);
        float qv[8] = {q0[0], q0[1], q0[2], q0[3], q1[0], q1[1], q1[2], q1[3]};

        float qacc[8], wfv[8], b1v[8], svp = 0.f;
#pragma unroll
        for (int s = 0; s < 8; ++s) qacc[s] = 0.f;

#pragma unroll
        for (int t = 0; t < NTILES; ++t) {
            const float* bptr =
                (t < 16) ? (w1_b + t * 16) :
                (t < 18) ? (wf_b + (t - 16) * 16) :
                (t < 20) ? (b1_b + (t - 18) * 16) : (v1_b + (t - 20) * 16);
            float4v bb = *(const float4v*)(bptr + quad * 4);
            float vb[4];
#pragma unroll
            for (int j = 0; j < 4; ++j) vb[j] = acc[g][t][j] + bb[j];

            if (t < 16) {              // w1: agent a = t>>1, slot base = (t&1)*4
                float q = qv[t >> 1];
                int base = (t & 1) * 4;
#pragma unroll
                for (int j = 0; j < 4; ++j) qacc[base + j] += q * fabsf(vb[j]);
            } else if (t < 18) {       // w_final
                int base = (t - 16) * 4;
#pragma unroll
                for (int j = 0; j < 4; ++j) wfv[base + j] = fabsf(vb[j]);
            } else if (t < 20) {       // b1
                int base = (t - 18) * 4;
#pragma unroll
                for (int j = 0; j < 4; ++j) b1v[base + j] = vb[j];
            } else {                   // V hidden: relu -> dot v2_W
                int ebase = (t - 20) * 16 + quad * 4;
#pragma unroll
                for (int j = 0; j < 4; ++j)
                    svp += fmaxf(vb[j], 0.f) * v2_W[ebase + j];
            }
        }

        float mix = 0.f;
#pragma unroll
        for (int s = 0; s < 8; ++s) {
            float h = qacc[s] + b1v[s];
            h = h > 0.f ? h : (__expf(h) - 1.f);   // elu, alpha=1
            mix += h * wfv[s];
        }
        float tot = mix + svp;                      // partial over this quad's e-subset
        tot += __shfl_xor(tot, 16);                 // combine 4 quads (same batch row)
        tot += __shfl_xor(tot, 32);
        if (quad == 0) out[row] = tot + v2_b[0];
    }
}

extern "C" void kernel_launch(void* const* d_in, const int* in_sizes, int n_in,
                              void* d_out, int out_size, void* d_ws, size_t ws_size,
                              hipStream_t stream) {
    const float* agent_qs = (const float*)d_in[0];
    const float* states   = (const float*)d_in[1];
    const float* w1_W = (const float*)d_in[2];
    const float* w1_b = (const float*)d_in[3];
    const float* wf_W = (const float*)d_in[4];
    const float* wf_b = (const float*)d_in[5];
    const float* b1_W = (const float*)d_in[6];
    const float* b1_b = (const float*)d_in[7];
    const float* v1_W = (const float*)d_in[8];
    const float* v1_b = (const float*)d_in[9];
    const float* v2_W = (const float*)d_in[10];
    const float* v2_b = (const float*)d_in[11];
    float* out = (float*)d_out;
    unsigned short* brep = (unsigned short*)d_ws;    // 180224 B of scratch

    repack_b<<<44, 256, 0, stream>>>(w1_W, wf_W, b1_W, v1_W, brep);
    qmix_main<<<512, 256, 0, stream>>>(agent_qs, states, brep,
                                       w1_b, wf_b, b1_b, v1_b, v2_W, v2_b, out);
}